// Round 1
// baseline (384.863 us; speedup 1.0000x reference)
//
#include <hip/hip_runtime.h>
#include <hip/hip_fp16.h>
#include <cstdint>

// ---------- types ----------
typedef _Float16 half8 __attribute__((ext_vector_type(8)));
typedef _Float16 half4 __attribute__((ext_vector_type(4)));
typedef float floatx4 __attribute__((ext_vector_type(4)));

#define S_TOT 8192
#define H_DIM 1152
#define NHEAD 16
#define HD 72
#define QSTR 96      // Q row stride (els), zeros in 72..95
#define KSTR 104     // K row stride (els), zeros in 72..103
#define PSTR 76      // P LDS row stride (bank-spread: 38 dw == 6 mod 32)
#define VSTR 76      // V^T tile row stride
#define VT_TILE 6080 // 80*76 els per (n,h,kb) V^T tile
#define NSEG 8
#define SEGL 1024
// 72^-0.5 * log2(e): exp2-based softmax, scale folded into Q
#define QSCALE 0.17002324631230988f

// async global->LDS 16B; LDS side is wave-uniform base + lane*16 (global side per-lane free)
__device__ __forceinline__ void gld_lds16(const void* g, void* l) {
  __builtin_amdgcn_global_load_lds((const __attribute__((address_space(1))) void*)g,
                                   (__attribute__((address_space(3))) void*)l, 16, 0, 0);
}

// ---------- elementwise cast fp32 -> f16 ----------
__global__ void cast_f32_f16(const float* __restrict__ in, _Float16* __restrict__ out, int n) {
  int i = (blockIdx.x * 256 + threadIdx.x) * 4;
  if (i < n) {
    float4 v = *(const float4*)(in + i);
    half4 o = { (_Float16)v.x, (_Float16)v.y, (_Float16)v.z, (_Float16)v.w };
    *(half4*)(out + i) = o;
  }
}

// ---------- transpose + cast: W[R][C] fp32 -> Wt[C][R] f16 ----------
__global__ void transpose_cast(const float* __restrict__ W, _Float16* __restrict__ Wt,
                               int R, int C) {
  __shared__ float tile[32][33];
  int tx = threadIdx.x, ty = threadIdx.y;          // (32,8)
  int bx = blockIdx.x, by = blockIdx.y;
#pragma unroll
  for (int i = 0; i < 4; ++i)
    tile[ty + i * 8][tx] = W[(size_t)(by * 32 + ty + i * 8) * C + bx * 32 + tx];
  __syncthreads();
#pragma unroll
  for (int i = 0; i < 4; ++i)
    Wt[(size_t)(bx * 32 + ty + i * 8) * R + by * 32 + tx] = (_Float16)tile[tx][ty + i * 8];
}

// ---------- 256x256 8-phase GEMM: C[M][N] = A[M][K] @ Bt[N][K]^T + bias ----------
// 512 thr = 8 waves (2M x 4N), wave tile 128x64, BK=64 processed as 2 k-halves of 32.
// LDS 128 KiB dynamic: slot(kt&1)*64K + {A:0,B:32K} + kh*16K + [256 rows][32 els] (64B/row).
// Bank swizzle: 16B chunk cs stored/read at cs ^ ((row>>1)&3)  (global source pre-swizzled,
// LDS writes linear for global_load_lds; any 8 consecutive lanes' ds_read_b128 cover all 32 banks).
// Schedule: 8 phases/iter (2 K-tiles); counted vmcnt(4) at phases 4 & 8 only; setprio around MFMA.
template <bool OUT_HALF>
__global__ __launch_bounds__(512, 2) void gemm256(
    const _Float16* __restrict__ A, const _Float16* __restrict__ Bt,
    const float* __restrict__ bias, float* __restrict__ Cf, _Float16* __restrict__ Ch,
    int M, int N, int K, int NT, int NWG) {
  extern __shared__ half8 smem8[];
  char* smem = (char*)smem8;
  const int tid = threadIdx.x;
  const int lane = tid & 63;
  const int w = tid >> 6;
  const int quad = lane >> 4, l16 = lane & 15;
  const int wm = w >> 2, wn = w & 3;               // 2 x 4 waves

  // bijective XCD swizzle (NWG % 8 == 0 guaranteed by host)
  const int orig = blockIdx.x;
  const int wg = (orig & 7) * (NWG >> 3) + (orig >> 3);
  const int mt = wg / NT, nt = wg - mt * NT;
  const int m0 = mt * 256, n0 = nt * 256;

  // ---- staging geometry: chunk c = i*512+tid -> row=c>>2, cs=c&3, src col-chunk = cs^((row>>1)&3)
  const _Float16* pA[2];
  const _Float16* pB[2];
  char* ldst[2];
#pragma unroll
  for (int i = 0; i < 2; ++i) {
    int c = i * 512 + tid;
    int r = c >> 2, cs = c & 3;
    int col = ((cs ^ ((r >> 1) & 3)) << 3);
    pA[i] = A + (size_t)(m0 + r) * K + col;
    int br = n0 + r; if (br >= N) br = N - 1;      // clamp pad rows (outputs masked)
    pB[i] = Bt + (size_t)br * K + col;
    ldst[i] = smem + c * 16;
  }
  // ---- ds_read offsets (swizzled): chunk read at quad ^ ((l16>>1)&3)
  const int e2 = (l16 >> 1) & 3;
  const int rsl = (quad ^ e2) << 4;
  const int aoff = (wm * 128 + l16) * 64 + rsl;
  const int boff = 32768 + (wn * 64 + l16) * 64 + rsl;

  half8 af[4], bf[4];
  floatx4 acc[8][4] = {};

#define STA(s, kh, kcol) { \
  gld_lds16(pA[0] + (kcol) + (kh) * 32, ldst[0] + (s) * 65536 + (kh) * 16384); \
  gld_lds16(pA[1] + (kcol) + (kh) * 32, ldst[1] + (s) * 65536 + (kh) * 16384); }
#define STB(s, kh, kcol) { \
  gld_lds16(pB[0] + (kcol) + (kh) * 32, ldst[0] + (s) * 65536 + 32768 + (kh) * 16384); \
  gld_lds16(pB[1] + (kcol) + (kh) * 32, ldst[1] + (s) * 65536 + 32768 + (kh) * 16384); }
#define LDB4(s, kk) { \
  _Pragma("unroll") for (int in = 0; in < 4; ++in) \
    bf[in] = *(const half8*)(smem + (s) * 65536 + (kk) * 16384 + boff + in * 1024); }
#define LDA4(s, kk, imh) { \
  _Pragma("unroll") for (int j = 0; j < 4; ++j) \
    af[j] = *(const half8*)(smem + (s) * 65536 + (kk) * 16384 + aoff + ((imh) * 4 + j) * 1024); }
#define MFMA16(imh) { \
  __builtin_amdgcn_s_setprio(1); \
  _Pragma("unroll") for (int j = 0; j < 4; ++j) \
  _Pragma("unroll") for (int in = 0; in < 4; ++in) \
    acc[(imh) * 4 + j][in] = \
      __builtin_amdgcn_mfma_f32_16x16x32_f16(af[j], bf[in], acc[(imh) * 4 + j][in], 0, 0, 0); \
  __builtin_amdgcn_s_setprio(0); }
#define BAR() __builtin_amdgcn_s_barrier()
#define LGKM0() { asm volatile("s_waitcnt lgkmcnt(0)" ::: "memory"); __builtin_amdgcn_sched_barrier(0); }
#define VMW(n) asm volatile("s_waitcnt vmcnt(" #n ")" ::: "memory")

  // ---- prologue: kt0 full + kt1 kh0; leave 2 stages (4 loads) in flight
  STA(0, 0, 0); STB(0, 0, 0);
  STA(0, 1, 0); STB(0, 1, 0);
  STA(1, 0, 64); STB(1, 0, 64);
  VMW(4);
  BAR();

  const int NI = K >> 7;    // 128 cols (2 K-tiles) per iteration
#pragma unroll 1
  for (int it = 0; it < NI; ++it) {
    const int kt = it << 7;
    const bool nl = (it + 1 < NI);
    // p0: slot0 kk0 im0-3            | stage A(kt+64) kh1 -> s1
    LDB4(0, 0); LDA4(0, 0, 0);
    STA(1, 1, kt + 64);
    BAR(); LGKM0();
    MFMA16(0);
    BAR();
    // p1: slot0 kk0 im4-7            | stage B(kt+64) kh1 -> s1
    LDA4(0, 0, 1);
    STB(1, 1, kt + 64);
    BAR(); LGKM0();
    MFMA16(1);
    BAR();
    // p2: slot0 kk1 im0-3            | stage A(kt+128) kh0 -> s0
    LDB4(0, 1); LDA4(0, 1, 0);
    if (nl) STA(0, 0, kt + 128);
    BAR(); LGKM0();
    MFMA16(0);
    BAR();
    // p3: slot0 kk1 im4-7            | stage B(kt+128) kh0 -> s0   [vmcnt]
    LDA4(0, 1, 1);
    if (nl) STB(0, 0, kt + 128);
    BAR(); LGKM0();
    MFMA16(1);
    if (nl) { VMW(4); } else { VMW(0); }
    BAR();
    // p4: slot1 kk0 im0-3            | stage A(kt+128) kh1 -> s0
    LDB4(1, 0); LDA4(1, 0, 0);
    if (nl) STA(0, 1, kt + 128);
    BAR(); LGKM0();
    MFMA16(0);
    BAR();
    // p5: slot1 kk0 im4-7            | stage B(kt+128) kh1 -> s0
    LDA4(1, 0, 1);
    if (nl) STB(0, 1, kt + 128);
    BAR(); LGKM0();
    MFMA16(1);
    BAR();
    // p6: slot1 kk1 im0-3            | stage A(kt+192) kh0 -> s1
    LDB4(1, 1); LDA4(1, 1, 0);
    if (nl) STA(1, 0, kt + 192);
    BAR(); LGKM0();
    MFMA16(0);
    BAR();
    // p7: slot1 kk1 im4-7            | stage B(kt+192) kh0 -> s1   [vmcnt]
    LDA4(1, 1, 1);
    if (nl) STB(1, 0, kt + 192);
    BAR(); LGKM0();
    MFMA16(1);
    if (nl) VMW(4);
    BAR();
  }
#undef STA
#undef STB
#undef LDB4
#undef LDA4
#undef MFMA16
#undef BAR
#undef LGKM0
#undef VMW

  // ---- epilogue: C write (guard n < N for padded tiles)
#pragma unroll
  for (int im = 0; im < 8; ++im) {
    int m = m0 + wm * 128 + im * 16 + quad * 4;
#pragma unroll
    for (int in = 0; in < 4; ++in) {
      int n = n0 + wn * 64 + in * 16 + l16;
      if (n < N) {
        float b = bias[n];
#pragma unroll
        for (int r = 0; r < 4; ++r) {
          float v = acc[im][in][r] + b;
          if (OUT_HALF) Ch[(size_t)(m + r) * N + n] = (_Float16)v;
          else          Cf[(size_t)(m + r) * N + n] = v;
        }
      }
    }
  }
}

// ---------- RoPE Q,K: thread t owns output row t -> contiguous wave writes ----------
__global__ void rope_scatter(const _Float16* __restrict__ QKV,  // [S][3456]
                             const float* __restrict__ cosb,    // [S][72]
                             const float* __restrict__ sinb,
                             _Float16* __restrict__ Qo, _Float16* __restrict__ Ko) {
  int t = blockIdx.x * 256 + threadIdx.x;  // output row = (n*16+h)*1024 + l
  int l = t & 1023, h = (t >> 10) & 15, n = t >> 14;
  int s = n * SEGL + l;
  const _Float16* q = QKV + (size_t)s * 3456 + h * HD;
  const _Float16* k = q + H_DIM;
  const float* cs = cosb + (size_t)s * HD;
  const float* sn = sinb + (size_t)s * HD;
  size_t qo = (size_t)t * QSTR, ko = (size_t)t * KSTR;
  half8 z = {};
  {
    _Float16 qr[72], qv[72];
#pragma unroll
    for (int i = 0; i < 9; ++i) *(half8*)&qr[8 * i] = *(const half8*)(q + 8 * i);
#pragma unroll
    for (int d = 0; d < 36; ++d) {
      float c0 = cs[d], s0 = sn[d], c1 = cs[d + 36], s1 = sn[d + 36];
      float a = (float)qr[d], b = (float)qr[d + 36];
      qv[d]      = (_Float16)((a * c0 - b * s0) * QSCALE);
      qv[d + 36] = (_Float16)((b * c1 + a * s1) * QSCALE);
    }
#pragma unroll
    for (int i = 0; i < 9; ++i) *(half8*)(Qo + qo + 8 * i) = *(half8*)&qv[8 * i];
#pragma unroll
    for (int i = 9; i < 12; ++i) *(half8*)(Qo + qo + 8 * i) = z;
  }
  {
    _Float16 kr[72], kv[72];
#pragma unroll
    for (int i = 0; i < 9; ++i) *(half8*)&kr[8 * i] = *(const half8*)(k + 8 * i);
#pragma unroll
    for (int d = 0; d < 36; ++d) {
      float c0 = cs[d], s0 = sn[d], c1 = cs[d + 36], s1 = sn[d + 36];
      float a = (float)kr[d], b = (float)kr[d + 36];
      kv[d]      = (_Float16)(a * c0 - b * s0);
      kv[d + 36] = (_Float16)(b * c1 + a * s1);
    }
#pragma unroll
    for (int i = 0; i < 9; ++i) *(half8*)(Ko + ko + 8 * i) = *(half8*)&kv[8 * i];
#pragma unroll
    for (int i = 9; i < 13; ++i) *(half8*)(Ko + ko + 8 * i) = z;  // full 104: no holes
  }
}

// ---------- V pre-transpose -> Vt tiles [n,h,kb][d:80][76]; row d=72 = ones (l_s trick) ----------
__global__ __launch_bounds__(256) void transpose_v(const _Float16* __restrict__ QKV,
                                                   _Float16* __restrict__ Vt) {
  __shared__ __align__(16) _Float16 Vs[64 * 88];   // [key][d pad 88]
  const int tid = threadIdx.x;
  const int kb = blockIdx.x, h = blockIdx.y, n = blockIdx.z;
  const int s0 = n * SEGL + kb * 64;
  const _Float16* src = QKV + (size_t)s0 * 3456 + 2 * H_DIM + h * HD;
  for (int idx = tid; idx < 576; idx += 256) {
    int key = idx / 9, c = idx - key * 9;
    *(half8*)&Vs[key * 88 + c * 8] = *(const half8*)(src + (size_t)key * 3456 + c * 8);
  }
  __syncthreads();
  _Float16* dst = Vt + (((size_t)(n * NHEAD + h)) * 16 + kb) * VT_TILE;
  for (int idx = tid; idx < 800; idx += 256) {  // 80 rows x 10 chunks
    int d = idx / 10, c = idx - d * 10;
    if (c < 8) {            // key cols 0..63
      half8 v = {};
      if (d < HD) {
#pragma unroll
        for (int j = 0; j < 8; ++j) v[j] = Vs[(c * 8 + j) * 88 + d];
      } else if (d == HD) { // ones row: PV MFMA accumulates sum(P) here
#pragma unroll
        for (int j = 0; j < 8; ++j) v[j] = (_Float16)1.0f;
      }
      *(half8*)(dst + d * VSTR + c * 8) = v;
    } else if (c == 8) {
      *(half8*)(dst + d * VSTR + 64) = half8{};  // pad cols 64..71
    } else {
      *(half4*)(dst + d * VSTR + 72) = half4{};  // pad cols 72..75
    }
  }
}

// ---------- flash attention (S^T), 32 q/wave, 128 q/block, grid 1024 ----------
// No max-tracking (scores bounded); l_s via ones-row in V^T (accumulated by PV MFMA).
__global__ __launch_bounds__(256, 3) void attn_kernel(
    const _Float16* __restrict__ Qb, const _Float16* __restrict__ Kb,
    const _Float16* __restrict__ Vtb, _Float16* __restrict__ Ctx) {
  __shared__ __align__(16) _Float16 Kt[64 * KSTR];     // 13312 B
  __shared__ __align__(16) _Float16 Vt[80 * VSTR];     // 12160 B
  __shared__ __align__(16) _Float16 Ps[4 * 16 * PSTR]; //  9728 B  (16 q rows per wave)
  const int tid = threadIdx.x;
  const int lane = tid & 63, w = tid >> 6;
  const int quad = lane >> 4, l16 = lane & 15;
  // swizzle: 8 qb-blocks of one (h,n) share id mod 8 -> same XCD L2
  const int id = blockIdx.x;
  const int hn = id & 127, qb = id >> 7;
  const int h = hn >> 3, n = hn & 7;
  const size_t hseg = (size_t)(n * NHEAD + h);
  const _Float16* Qg = Qb + hseg * SEGL * QSTR;
  const _Float16* Kg = Kb + hseg * SEGL * KSTR;
  const _Float16* Vg = Vtb + hseg * 16 * VT_TILE;

  half8 qf[2][3];
#pragma unroll
  for (int qg = 0; qg < 2; ++qg) {
    int row = qb * 128 + w * 32 + qg * 16 + l16;
#pragma unroll
    for (int kc = 0; kc < 3; ++kc)
      qf[qg][kc] = *(const half8*)(Qg + (size_t)row * QSTR + kc * 32 + quad * 8);
  }
  floatx4 o_acc[2][5] = {};   // O^T[d = t*16+quad*4+r][q]; t=4,quad=2,r=0 carries sum(P)

  for (int kb = 0; kb < SEGL / 64; ++kb) {
    __syncthreads();
    // K tile: contiguous 13312 B
    {
      const char* base = (const char*)(Kg + (size_t)kb * 64 * KSTR);
#pragma unroll
      for (int i = 0; i < 3; ++i)
        gld_lds16(base + tid * 16 + i * 4096, (char*)Kt + tid * 16 + i * 4096);
      if (tid < 64)
        gld_lds16(base + 12288 + tid * 16, (char*)Kt + 12288 + tid * 16);
    }
    // V^T tile: contiguous 12160 B
    {
      const char* base = (const char*)(Vg + (size_t)kb * VT_TILE);
#pragma unroll
      for (int i = 0; i < 2; ++i)
        gld_lds16(base + tid * 16 + i * 4096, (char*)Vt + tid * 16 + i * 4096);
      if (tid < 248)
        gld_lds16(base + 8192 + tid * 16, (char*)Vt + 8192 + tid * 16);
    }
    __syncthreads();
    // S^T = K·Q^T (K-frags shared across both q-groups)
    floatx4 sa[2][4] = {};
#pragma unroll
    for (int nt = 0; nt < 4; ++nt) {
      half8 kf[3];
#pragma unroll
      for (int kc = 0; kc < 3; ++kc)
        kf[kc] = *(const half8*)&Kt[(nt * 16 + l16) * KSTR + kc * 32 + quad * 8];
#pragma unroll
      for (int qg = 0; qg < 2; ++qg)
#pragma unroll
        for (int kc = 0; kc < 3; ++kc)
          sa[qg][nt] = __builtin_amdgcn_mfma_f32_16x16x32_f16(kf[kc], qf[qg][kc], sa[qg][nt], 0, 0, 0);
    }
    // p = exp2(s), no max subtraction; no explicit sum (ones-row handles it)
#pragma unroll
    for (int qg = 0; qg < 2; ++qg)
#pragma unroll
      for (int nt = 0; nt < 4; ++nt)
#pragma unroll
        for (int r = 0; r < 4; ++r)
          sa[qg][nt][r] = exp2f(sa[qg][nt][r]);
    // V-frags once per tile, reused across both q-groups
    half8 vf[2][5];
#pragma unroll
    for (int kc2 = 0; kc2 < 2; ++kc2)
#pragma unroll
      for (int t = 0; t < 5; ++t)
        vf[kc2][t] = *(const half8*)&Vt[(t * 16 + l16) * VSTR + kc2 * 32 + quad * 8];
    // per q-group: P -> LDS (wave-private 16 rows, reused across qg; in-order DS = safe)
#pragma unroll
    for (int qg = 0; qg < 2; ++qg) {
      int prow = (w * 16 + l16) * PSTR;
#pragma unroll
      for (int nt = 0; nt < 4; ++nt) {
        half4 ph = { (_Float16)sa[qg][nt][0], (_Float16)sa[qg][nt][1],
                     (_Float16)sa[qg][nt][2], (_Float16)sa[qg][nt][3] };
        *(half4*)&Ps[prow + nt * 16 + quad * 4] = ph;
      }
#pragma unroll
      for (int kc2 = 0; kc2 < 2; ++kc2) {
        half8 pb = *(const half8*)&Ps[(w * 16 + l16) * PSTR + kc2 * 32 + quad * 8];
#pragma unroll
        for (int t = 0; t < 5; ++t)
          o_acc[qg][t] = __builtin_amdgcn_mfma_f32_16x16x32_f16(vf[kc2][t], pb, o_acc[qg][t], 0, 0, 0);
      }
    }
  }
  // epilogue: l = sum(P) lives at t=4, quad=2, r=0 -> broadcast from lane 32+l16
#pragma unroll
  for (int qg = 0; qg < 2; ++qg) {
    float lsum = __shfl(o_acc[qg][4][0], 32 + l16, 64);
    float rl = 1.0f / lsum;
    size_t s2 = (size_t)n * SEGL + qb * 128 + w * 32 + qg * 16 + l16;
#pragma unroll
    for (int t = 0; t < 5; ++t) {
      int d0 = t * 16 + quad * 4;
      if (d0 < HD) {
        half4 hv = { (_Float16)(o_acc[qg][t][0] * rl), (_Float16)(o_acc[qg][t][1] * rl),
                     (_Float16)(o_acc[qg][t][2] * rl), (_Float16)(o_acc[qg][t][3] * rl) };
        *(half4*)&Ctx[s2 * H_DIM + h * HD + d0] = hv;
      }
    }
  }
}

extern "C" void kernel_launch(void* const* d_in, const int* in_sizes, int n_in,
                              void* d_out, int out_size, void* d_ws, size_t ws_size,
                              hipStream_t stream) {
  const float* X    = (const float*)d_in[0];
  const float* cosb = (const float*)d_in[1];
  const float* sinb = (const float*)d_in[2];
  const float* Wqkv = (const float*)d_in[3];
  const float* bqkv = (const float*)d_in[4];
  const float* Wout = (const float*)d_in[5];
  const float* bout = (const float*)d_in[6];
  float* out = (float*)d_out;
  char* ws = (char*)d_ws;

  _Float16* Xb   = (_Float16*)(ws);              // 18,874,368 (reused as Ctx)
  _Float16* Wqt  = (_Float16*)(ws + 18874368);   //  7,962,624
  _Float16* Wot  = (_Float16*)(ws + 26836992);   //  2,654,208
  _Float16* QKVb = (_Float16*)(ws + 29491200);   // 56,623,104
  _Float16* Qb   = (_Float16*)(ws + 86114304);   // 25,165,824
  _Float16* Kb   = (_Float16*)(ws + 111280128);  // 27,262,976
  _Float16* Vtb  = (_Float16*)(ws + 138543104);  // 24,903,680
  _Float16* Ctx  = Xb;

  static bool attr_done = false;
  if (!attr_done) {
    hipFuncSetAttribute(reinterpret_cast<const void*>(gemm256<true>),
                        hipFuncAttributeMaxDynamicSharedMemorySize, 131072);
    hipFuncSetAttribute(reinterpret_cast<const void*>(gemm256<false>),
                        hipFuncAttributeMaxDynamicSharedMemorySize, 131072);
    attr_done = true;
  }

  cast_f32_f16<<<9216, 256, 0, stream>>>(X, Xb, S_TOT * H_DIM);
  transpose_cast<<<dim3(108, 36), dim3(32, 8), 0, stream>>>(Wqkv, Wqt, H_DIM, 3 * H_DIM);
  transpose_cast<<<dim3(36, 36), dim3(32, 8), 0, stream>>>(Wout, Wot, H_DIM, H_DIM);
  // QKV: M=8192, N=3456 (14 tiles, last masked), K=1152 -> 448 wg (%8==0)
  gemm256<true><<<448, 512, 131072, stream>>>(Xb, Wqt, bqkv, nullptr, QKVb,
                                              S_TOT, 3 * H_DIM, H_DIM, 14, 448);
  rope_scatter<<<512, 256, 0, stream>>>(QKVb, cosb, sinb, Qb, Kb);
  transpose_v<<<dim3(16, 16, 8), 256, 0, stream>>>(QKVb, Vtb);
  attn_kernel<<<1024, 256, 0, stream>>>(Qb, Kb, Vtb, Ctx);
  // out: M=8192, N=1152 (5 tiles, last masked), K=1152 -> 160 wg (%8==0)
  gemm256<false><<<160, 512, 131072, stream>>>(Ctx, Wot, bout, out, nullptr,
                                               S_TOT, H_DIM, H_DIM, 5, 160);
}